// Round 9
// baseline (794.889 us; speedup 1.0000x reference)
//
#include <hip/hip_runtime.h>
#include <hip/hip_bf16.h>
#include <math.h>

#define BQ 32
#define SQ 2048
#define DQ 1024
#define NQ 512
#define MQ (BQ*SQ)
#define BM 256
#define BN 512
#define BK 32
#define AP 40   // padded A row stride (shorts): 80B, 16B-aligned, bank-spread

typedef __attribute__((ext_vector_type(8))) short bf16x8;
typedef __attribute__((ext_vector_type(4))) float f32x4;

// compiler-path f32->bf16 (RTNE, pairs into v_cvt_pk_bf16_f32)
__device__ __forceinline__ short f2bf(float f){
  return __builtin_bit_cast(short, __float2bfloat16(f));
}

__device__ __forceinline__ void gload_lds16(const void* g, void* l){
  __builtin_amdgcn_global_load_lds(
      (const __attribute__((address_space(1))) unsigned int*)g,
      (__attribute__((address_space(3))) unsigned int*)l, 16, 0, 0);
}

// ---- prep: transpose gate_w1 [K=1024][N=512] -> bf16 w1t [N=512][K=1024]
__global__ void k_w1t(const float* __restrict__ w1, short* __restrict__ w1t){
  int i = blockIdx.x*256 + threadIdx.x;
  if (i >= NQ*DQ) return;
  int n = i >> 10, k = i & (DQ-1);
  w1t[i] = f2bf(w1[(size_t)k*NQ + n]);
}

// ---- prep: wq[d] = key_w[d,:]·q (d<1024); wq[1024] = key_b·q
__global__ void k_wq(const float* __restrict__ kw, const float* __restrict__ kb,
                     const float* __restrict__ q, float* __restrict__ wq){
  __shared__ float sh[4];
  int d = blockIdx.x, t = threadIdx.x;
  const float* row = (d < DQ) ? (kw + (size_t)d*DQ) : kb;
  float s = 0.f;
  for (int e=t;e<DQ;e+=256) s += row[e]*q[e];
  #pragma unroll
  for (int o=32;o;o>>=1) s += __shfl_down(s,o);
  if ((t&63)==0) sh[t>>6]=s;
  __syncthreads();
  if (t==0) wq[d] = sh[0]+sh[1]+sh[2]+sh[3];
}

// ---- mask dtype detector: 0=int32(0/1), 1=float32(0/1.0f), 2=byte(bool)
__global__ void k_det(const unsigned int* __restrict__ m, int* __restrict__ flag){
  __shared__ int so, sf;
  int t = threadIdx.x;
  if (t==0){ so=0; sf=0; }
  __syncthreads();
  int o=0, f1=0;
  for (int i=t;i<MQ/4;i+=256){
    unsigned v = m[i];
    if (v==0x3F800000u) f1=1;
    else if (v>1u) o=1;
  }
  if (o) atomicOr(&so,1);
  if (f1) atomicOr(&sf,1);
  __syncthreads();
  if (t==0) *flag = so?2:(sf?1:0);
}

// ---- per-batch valid length (reads flag; stream-ordered after k_det)
__global__ __launch_bounds__(256) void k_len(const void* __restrict__ maskp,
                                             const int* __restrict__ flag,
                                             int* __restrict__ lens){
  __shared__ int sh[4];
  int b = blockIdx.x, t = threadIdx.x;
  int fl = *flag;
  const unsigned char* m8 = (const unsigned char*)maskp;
  const float* mf = (const float*)maskp;
  const int* mi = (const int*)maskp;
  int cnt = 0;
  #pragma unroll
  for (int i=0;i<8;i++){
    size_t idx = (size_t)b*SQ + t + i*256;
    int mm = (fl==2) ? (m8[idx]!=0) : (fl==1) ? (mf[idx]!=0.0f) : (mi[idx]!=0);
    cnt += mm^1;
  }
  #pragma unroll
  for (int o=32;o;o>>=1) cnt += __shfl_down(cnt,o);
  if ((t&63)==0) sh[t>>6]=cnt;
  __syncthreads();
  if (t==0) lens[b] = sh[0]+sh[1]+sh[2]+sh[3];
}

// ---- fused: h=x@W1 (MFMA, LDS dbuf) -> gate -> e=exp(dec), w=e*gate -> pool.
// 256x512 tile (full N), BK=32, 1024 threads = 16 waves (4wm x 4wn),
// wave tile 64x128 (acc 4x8). One block per CU (grid=256).
__global__ __launch_bounds__(1024, 4) void k_gate(
    const float* __restrict__ x, const short* __restrict__ w1t,
    const float* __restrict__ wq, const float* __restrict__ w2,
    const float* __restrict__ b1, const float* __restrict__ b2p,
    const float* __restrict__ lamp,
    const void* __restrict__ maskp, const int* __restrict__ flag,
    const int* __restrict__ lens,
    float* __restrict__ part, float* __restrict__ wsum)
{
  __shared__ __align__(16) short As[2][BM*AP];   // 20KB x2
  __shared__ __align__(16) short Bs[2][BN*BK];   // 32KB x2
  __shared__ float wqs[DQ];                       // 4KB
  __shared__ float red[4][BM];                    // 4KB
  __shared__ float wrow[BM];                      // 1KB
  __shared__ float xqrow[BM];                     // 1KB
  __shared__ float swsum[4];

  int tid = threadIdx.x;
  int bm = blockIdx.x;
  int m0 = bm*BM;
  int batch = bm >> 3;           // 8 s-chunks of 256 per batch
  int sBase = (bm & 7) * 256;
  int lane = tid & 63, wid = tid >> 6;
  int wm = wid >> 2, wn = wid & 3;
  int lo = lane & 15, hi = lane >> 4;

  wqs[tid] = wq[tid];

  // A staging: thread t -> row t>>2 (0..255), float cols (t&3)*8 .. +8
  int ar = tid >> 2, acf = (tid & 3) * 8, acs = (tid & 3) * 8;
  const float* asrc = x + (size_t)(m0 + ar)*DQ + acf;
  // B staging: issue i covers rows i*256+(t>>2); LDS shorts i*8192 + t*8
  const short* bsrc0 = w1t + (size_t)(tid>>2)*DQ + (tid&3)*8;

  float w2v[8], b1v[8];
  #pragma unroll
  for (int fn=0;fn<8;fn++){
    int n = wn*128 + fn*16 + lo;
    w2v[fn] = w2[n]; b1v[fn] = b1[n];
  }

  // ---- prologue: stage k0=0
  f32x4 rAa = *(const f32x4*)(asrc);
  f32x4 rAb = *(const f32x4*)(asrc + 4);
  gload_lds16(bsrc0,                    &Bs[0][tid*8]);
  gload_lds16(bsrc0 + (size_t)256*DQ,   &Bs[0][8192 + tid*8]);
  __syncthreads();   // wqs visible; Bs[0] drained (barrier implies vmcnt(0))
  float xqacc = 0.f;
  {
    f32x4 w0 = *(const f32x4*)(wqs + acf);
    f32x4 w1v = *(const f32x4*)(wqs + acf + 4);
    #pragma unroll
    for (int j=0;j<4;j++) xqacc += rAa[j]*w0[j] + rAb[j]*w1v[j];
    bf16x8 sv;
    #pragma unroll
    for (int j=0;j<4;j++){ sv[j]=f2bf(rAa[j]); sv[4+j]=f2bf(rAb[j]); }
    *(bf16x8*)(&As[0][ar*AP + acs]) = sv;
  }
  __syncthreads();

  f32x4 acc[4][8];
  #pragma unroll
  for (int a=0;a<4;a++)
    #pragma unroll
    for (int b=0;b<8;b++) acc[a][b] = (f32x4){0.f,0.f,0.f,0.f};

  for (int t=0;t<32;t++){
    int cur = t & 1, nxt = cur ^ 1;
    int kn = (t+1)*BK;
    if (t < 31){
      rAa = *(const f32x4*)(asrc + kn);
      rAb = *(const f32x4*)(asrc + kn + 4);
      gload_lds16(bsrc0 + kn,                  &Bs[nxt][tid*8]);
      gload_lds16(bsrc0 + (size_t)256*DQ + kn, &Bs[nxt][8192 + tid*8]);
    }
    bf16x8 af[4], bfr[8];
    #pragma unroll
    for (int fm=0;fm<4;fm++)
      af[fm] = *(const bf16x8*)(&As[cur][(wm*64+fm*16+lo)*AP + hi*8]);
    #pragma unroll
    for (int fn=0;fn<8;fn++)
      bfr[fn] = *(const bf16x8*)(&Bs[cur][(wn*128+fn*16+lo)*BK + hi*8]);
    #pragma unroll
    for (int fm=0;fm<4;fm++)
      #pragma unroll
      for (int fn=0;fn<8;fn++)
        acc[fm][fn] = __builtin_amdgcn_mfma_f32_16x16x32_bf16(af[fm], bfr[fn], acc[fm][fn], 0,0,0);
    if (t < 31){
      f32x4 w0 = *(const f32x4*)(wqs + kn + acf);
      f32x4 w1v = *(const f32x4*)(wqs + kn + acf + 4);
      #pragma unroll
      for (int j=0;j<4;j++) xqacc += rAa[j]*w0[j] + rAb[j]*w1v[j];
      bf16x8 sv;
      #pragma unroll
      for (int j=0;j<4;j++){ sv[j]=f2bf(rAa[j]); sv[4+j]=f2bf(rAb[j]); }
      *(bf16x8*)(&As[nxt][ar*AP + acs]) = sv;
    }
    __syncthreads();
  }

  // xq: combine 4 threads per row
  {
    float s = xqacc;
    s += __shfl_xor(s,1); s += __shfl_xor(s,2);
    if ((tid & 3) == 0) xqrow[ar] = s;
  }

  // gate partials: GELU + dot w2 over this wave's 128 cols
  #pragma unroll
  for (int fm=0;fm<4;fm++){
    #pragma unroll
    for (int j=0;j<4;j++){
      float s = 0.f;
      #pragma unroll
      for (int fn=0;fn<8;fn++){
        float h = acc[fm][fn][j] + b1v[fn];
        float g = 0.5f*h*(1.0f + erff(h*0.70710678118f));
        s += g*w2v[fn];
      }
      s += __shfl_xor(s,1); s += __shfl_xor(s,2);
      s += __shfl_xor(s,4); s += __shfl_xor(s,8);
      if (lo == 0) red[wn][wm*64 + fm*16 + hi*4 + j] = s;
    }
  }
  __syncthreads();

  // w phase: threads 0..255 compute e=exp(dec) (denom) and wrow=e*gate (numer)
  if (tid < BM){
    int s = sBase + tid;
    float gsum = b2p[0] + red[0][tid] + red[1][tid] + red[2][tid] + red[3][tid];
    float gate = 1.0f/(1.0f+expf(-gsum));
    float qb = wq[DQ];
    float lg = (gate*xqrow[tid] + qb)*0.03125f;
    float lam = lamp[0];
    float posl = fmaxf(lam,0.f) + log1pf(expf(-fabsf(lam)));
    int L = lens[batch];
    float pen = fmaxf((float)L - 1.0f - (float)s, 0.0f);
    int fl = *flag;
    size_t mi_ = (size_t)batch*SQ + s;
    int mm = (fl==2) ? (((const unsigned char*)maskp)[mi_]!=0)
           : (fl==1) ? (((const float*)maskp)[mi_]!=0.0f)
                     : (((const int*)maskp)[mi_]!=0);
    float e = mm ? 0.0f : expf(lg - posl*pen);   // softmax denominator term
    wrow[tid] = e*gate;                           // pooling weight
    float tsum = e;
    #pragma unroll
    for (int o=1;o<64;o<<=1) tsum += __shfl_xor(tsum,o);
    if (lane==0) swsum[wid] = tsum;
  }
  __syncthreads();
  if (tid==0) wsum[bm] = swsum[0]+swsum[1]+swsum[2]+swsum[3];

  // pooling: part[bm][d] = sum_s wrow_s * x[m0+s][d]  (x tile is L2/L3-hot)
  {
    int d = tid;
    const float* xb = x + (size_t)m0*DQ + d;
    float a0 = 0.f;
    #pragma unroll 8
    for (int s=0;s<BM;s++){
      a0 += wrow[s] * xb[(size_t)s*DQ];
    }
    part[(size_t)bm*DQ + d] = a0;
  }
}

// ---- final: out[b][d] = sum_c part[b*8+c][d] / sum_c wsum[b*8+c]
__global__ __launch_bounds__(256) void k_fin(const float* __restrict__ part,
                                             const float* __restrict__ wsum,
                                             float* __restrict__ out){
  int i = blockIdx.x*256 + threadIdx.x;   // 32768
  int b = i >> 10, d = i & 1023;
  float den = 0.f;
  #pragma unroll
  for (int c=0;c<8;c++) den += wsum[b*8+c];
  float s = 0.f;
  #pragma unroll
  for (int c=0;c<8;c++) s += part[((size_t)(b*8+c))*DQ + d];
  out[i] = s/den;
}

extern "C" void kernel_launch(void* const* d_in, const int* in_sizes, int n_in,
                              void* d_out, int out_size, void* d_ws, size_t ws_size,
                              hipStream_t stream)
{
  const float* x    = (const float*)d_in[0];
  const void*  mask = d_in[1];
  const float* w1   = (const float*)d_in[2];
  const float* b1   = (const float*)d_in[3];
  const float* w2   = (const float*)d_in[4];
  const float* b2   = (const float*)d_in[5];
  const float* lam  = (const float*)d_in[6];
  const float* q    = (const float*)d_in[7];
  const float* kw   = (const float*)d_in[8];
  const float* kb   = (const float*)d_in[9];
  char* ws = (char*)d_ws;
  short* w1t = (short*)ws;                               // 1 MB
  float* wq  = (float*)(ws + (1<<20));                   // 8 KB (1025 floats)
  int* flag  = (int*)(ws + (1<<20) + 8192);              // 4 B
  int* lens  = (int*)(ws + (1<<20) + 8448);              // 128 B
  float* wsum= (float*)(ws + (1<<20) + 12544);           // 1 KB (256 floats)
  float* part= (float*)(ws + (1<<20) + 20736);           // 1 MB (256x1024)
  float* out = (float*)d_out;

  k_w1t<<<dim3((NQ*DQ+255)/256), 256, 0, stream>>>(w1, w1t);
  k_wq<<<dim3(DQ+1), 256, 0, stream>>>(kw, kb, q, wq);
  k_det<<<dim3(1), 256, 0, stream>>>((const unsigned int*)mask, flag);
  k_len<<<dim3(BQ), 256, 0, stream>>>(mask, flag, lens);
  k_gate<<<dim3(MQ/BM), 1024, 0, stream>>>(x, w1t, wq, w2, b1, b2, lam,
                                           mask, flag, lens, part, wsum);
  k_fin<<<dim3((BQ*DQ)/256), 256, 0, stream>>>(part, wsum, out);
}

// Round 10
// 283.319 us; speedup vs baseline: 2.8056x; 2.8056x over previous
//
#include <hip/hip_runtime.h>
#include <hip/hip_bf16.h>
#include <math.h>

#define BQ 32
#define SQ 2048
#define DQ 1024
#define NQ 512
#define MQ (BQ*SQ)
#define BM 64
#define BN 512
#define BK 32

typedef __attribute__((ext_vector_type(8))) short bf16x8;
typedef __attribute__((ext_vector_type(4))) short bf16x4;
typedef __attribute__((ext_vector_type(4))) float f32x4;

// compiler-path f32->bf16 (RTNE, pairs into v_cvt_pk_bf16_f32)
__device__ __forceinline__ short f2bf(float f){
  return __builtin_bit_cast(short, __float2bfloat16(f));
}

__device__ __forceinline__ void gload_lds16(const void* g, void* l){
  __builtin_amdgcn_global_load_lds(
      (const __attribute__((address_space(1))) unsigned int*)g,
      (__attribute__((address_space(3))) unsigned int*)l, 16, 0, 0);
}

// ---- prep: transpose gate_w1 [K=1024][N=512] -> bf16 w1t [N=512][K=1024]
__global__ void k_w1t(const float* __restrict__ w1, short* __restrict__ w1t){
  int i = blockIdx.x*256 + threadIdx.x;
  if (i >= NQ*DQ) return;
  int n = i >> 10, k = i & (DQ-1);
  w1t[i] = f2bf(w1[(size_t)k*NQ + n]);
}

// ---- prep: wq[d] = key_w[d,:]·q (d<1024); wq[1024] = key_b·q
__global__ void k_wq(const float* __restrict__ kw, const float* __restrict__ kb,
                     const float* __restrict__ q, float* __restrict__ wq){
  __shared__ float sh[4];
  int d = blockIdx.x, t = threadIdx.x;
  const float* row = (d < DQ) ? (kw + (size_t)d*DQ) : kb;
  float s = 0.f;
  for (int e=t;e<DQ;e+=256) s += row[e]*q[e];
  #pragma unroll
  for (int o=32;o;o>>=1) s += __shfl_down(s,o);
  if ((t&63)==0) sh[t>>6]=s;
  __syncthreads();
  if (t==0) wq[d] = sh[0]+sh[1]+sh[2]+sh[3];
}

// ---- mask dtype detector: 0=int32(0/1), 1=float32(0/1.0f), 2=byte(bool)
__global__ void k_det(const unsigned int* __restrict__ m, int* __restrict__ flag){
  __shared__ int so, sf;
  int t = threadIdx.x;
  if (t==0){ so=0; sf=0; }
  __syncthreads();
  int o=0, f1=0;
  for (int i=t;i<MQ/4;i+=256){
    unsigned v = m[i];
    if (v==0x3F800000u) f1=1;
    else if (v>1u) o=1;
  }
  if (o) atomicOr(&so,1);
  if (f1) atomicOr(&sf,1);
  __syncthreads();
  if (t==0) *flag = so?2:(sf?1:0);
}

// ---- per-batch valid length (reads flag; stream-ordered after k_det)
__global__ __launch_bounds__(256) void k_len(const void* __restrict__ maskp,
                                             const int* __restrict__ flag,
                                             int* __restrict__ lens){
  __shared__ int sh[4];
  int b = blockIdx.x, t = threadIdx.x;
  int fl = *flag;
  const unsigned char* m8 = (const unsigned char*)maskp;
  const float* mf = (const float*)maskp;
  const int* mi = (const int*)maskp;
  int cnt = 0;
  #pragma unroll
  for (int i=0;i<8;i++){
    size_t idx = (size_t)b*SQ + t + i*256;
    int mm = (fl==2) ? (m8[idx]!=0) : (fl==1) ? (mf[idx]!=0.0f) : (mi[idx]!=0);
    cnt += mm^1;
  }
  #pragma unroll
  for (int o=32;o;o>>=1) cnt += __shfl_down(cnt,o);
  if ((t&63)==0) sh[t>>6]=cnt;
  __syncthreads();
  if (t==0) lens[b] = sh[0]+sh[1]+sh[2]+sh[3];
}

// ---- fused: h=x@W1 (MFMA, LDS dbuf, thin loop) -> xq L2 pass -> gate ->
//      e=exp(dec), w=e*gate -> partial pool.
// 64x512 tile (full N), BK=32, 512 threads = 8 waves over N, wave tile 64x64.
__global__ __launch_bounds__(512) void k_gate(
    const float* __restrict__ x, const short* __restrict__ w1t,
    const float* __restrict__ wq, const float* __restrict__ w2,
    const float* __restrict__ b1, const float* __restrict__ b2p,
    const float* __restrict__ lamp,
    const void* __restrict__ maskp, const int* __restrict__ flag,
    const int* __restrict__ lens,
    float* __restrict__ part, float* __restrict__ wsum)
{
  __shared__ __align__(16) short As[2][BM*BK];   // 4KB x2
  __shared__ __align__(16) short Bs[2][BN*BK];   // 32KB x2
  __shared__ float red[8][BM];                    // 2KB
  __shared__ float wrow[BM];
  __shared__ float xqrow[BM];

  int tid = threadIdx.x;
  int bm = blockIdx.x;
  int m0 = bm*BM;
  int batch = bm >> 5;          // 32 s-chunks of 64 per batch
  int sBase = (bm & 31) * 64;
  int lane = tid & 63, wid = tid >> 6;
  int wn = wid;                 // 8 waves across N=512
  int lo = lane & 15, hi = lane >> 4;

  // A staging: thread t -> row t>>3 (0..63), cols (t&7)*4 .. +4
  int ar = tid >> 3, ac = (tid & 7) * 4;
  const float* asrc = x + (size_t)(m0 + ar)*DQ + ac;
  // B staging: issue i covers rows i*128+(t>>2); LDS shorts i*4096 + t*8
  const short* bsrc = w1t + (size_t)(tid>>2)*DQ + (tid&3)*8;

  float w2v[4], b1v[4];
  #pragma unroll
  for (int fn=0;fn<4;fn++){
    int n = wn*64 + fn*16 + lo;
    w2v[fn] = w2[n]; b1v[fn] = b1[n];
  }

  // ---- prologue: stage k-chunk 0; issue chunk-1 A load (distance-2 pipe)
  f32x4 rA0 = *(const f32x4*)(asrc);
  #pragma unroll
  for (int i=0;i<4;i++)
    gload_lds16(bsrc + (size_t)i*128*DQ, &Bs[0][i*4096 + tid*8]);
  f32x4 rA1 = *(const f32x4*)(asrc + BK);
  {
    bf16x4 sv;
    #pragma unroll
    for (int j=0;j<4;j++) sv[j]=f2bf(rA0[j]);
    *(bf16x4*)(&As[0][ar*BK + ac]) = sv;
  }
  __syncthreads();   // As[0] + Bs[0] ready (barrier implies vmcnt/lgkm drain)

  f32x4 acc[4][4];
  #pragma unroll
  for (int a=0;a<4;a++)
    #pragma unroll
    for (int b=0;b<4;b++) acc[a][b] = (f32x4){0.f,0.f,0.f,0.f};

  f32x4 rA2 = rA1;
  for (int t=0;t<32;t++){
    int cur = t & 1, nxt = cur ^ 1;
    int kn = (t+1)*BK;
    if (t < 31){
      #pragma unroll
      for (int i=0;i<4;i++)
        gload_lds16(bsrc + (size_t)i*128*DQ + kn, &Bs[nxt][i*4096 + tid*8]);
    }
    if (t < 30){
      rA2 = *(const f32x4*)(asrc + kn + BK);   // chunk t+2, ~1.5 steps of cover
    }
    bf16x8 af[4], bfr[4];
    #pragma unroll
    for (int fm=0;fm<4;fm++)
      af[fm] = *(const bf16x8*)(&As[cur][(fm*16+lo)*BK + hi*8]);
    #pragma unroll
    for (int fn=0;fn<4;fn++)
      bfr[fn] = *(const bf16x8*)(&Bs[cur][(wn*64+fn*16+lo)*BK + hi*8]);
    #pragma unroll
    for (int fm=0;fm<4;fm++)
      #pragma unroll
      for (int fn=0;fn<4;fn++)
        acc[fm][fn] = __builtin_amdgcn_mfma_f32_16x16x32_bf16(af[fm], bfr[fn], acc[fm][fn], 0,0,0);
    if (t < 31){
      bf16x4 sv;
      #pragma unroll
      for (int j=0;j<4;j++) sv[j]=f2bf(rA1[j]);
      *(bf16x4*)(&As[nxt][ar*BK + ac]) = sv;
      rA1 = rA2;
    }
    __syncthreads();
  }

  // gate partials: GELU + dot w2 over this wave's 64 cols
  #pragma unroll
  for (int fm=0;fm<4;fm++){
    #pragma unroll
    for (int j=0;j<4;j++){
      float s = 0.f;
      #pragma unroll
      for (int fn=0;fn<4;fn++){
        float h = acc[fm][fn][j] + b1v[fn];
        float g = 0.5f*h*(1.0f + erff(h*0.70710678118f));
        s += g*w2v[fn];
      }
      s += __shfl_xor(s,1); s += __shfl_xor(s,2);
      s += __shfl_xor(s,4); s += __shfl_xor(s,8);
      if (lo == 0) red[wid][fm*16 + hi*4 + j] = s;
    }
  }

  // xq pass: re-read this block's x tile from L2 (hot) against global wq.
  // row r = tid>>3 handled by 8 threads, each a 128-float segment.
  {
    int xr = tid >> 3;
    int xo = (tid & 7) * 128;
    const float* xrow = x + (size_t)(m0 + xr)*DQ + xo;
    const float* wqo  = wq + xo;
    float s = 0.f;
    #pragma unroll 8
    for (int i=0;i<32;i++){
      f32x4 v = *(const f32x4*)(xrow + i*4);
      f32x4 w = *(const f32x4*)(wqo + i*4);
      s += v[0]*w[0] + v[1]*w[1] + v[2]*w[2] + v[3]*w[3];
    }
    s += __shfl_xor(s,1); s += __shfl_xor(s,2); s += __shfl_xor(s,4);
    if ((tid & 7) == 0) xqrow[xr] = s;
  }
  __syncthreads();

  // w phase: wave 0 computes e=exp(dec) (denominator) and wrow=e*gate (numerator)
  if (tid < 64){
    int s = sBase + tid;
    float gsum = b2p[0];
    #pragma unroll
    for (int w=0;w<8;w++) gsum += red[w][tid];
    float gate = 1.0f/(1.0f+expf(-gsum));
    float qb = wq[DQ];
    float lg = (gate*xqrow[tid] + qb)*0.03125f;
    float lam = lamp[0];
    float posl = fmaxf(lam,0.f) + log1pf(expf(-fabsf(lam)));
    int L = lens[batch];
    float pen = fmaxf((float)L - 1.0f - (float)s, 0.0f);
    int fl = *flag;
    size_t mi_ = (size_t)batch*SQ + s;
    int mm = (fl==2) ? (((const unsigned char*)maskp)[mi_]!=0)
           : (fl==1) ? (((const float*)maskp)[mi_]!=0.0f)
                     : (((const int*)maskp)[mi_]!=0);
    float e = mm ? 0.0f : expf(lg - posl*pen);   // softmax denominator term
    wrow[tid] = e*gate;                           // pooling weight
    float tsum = e;
    #pragma unroll
    for (int o=1;o<64;o<<=1) tsum += __shfl_xor(tsum,o);
    if (tid==0) wsum[bm] = tsum;
  }
  __syncthreads();

  // pooling: part[bm][d] = sum_s wrow_s * x[m0+s][d]  (x tile is L2-hot)
  {
    int d0 = tid*2;
    const float* xb = x + (size_t)m0*DQ + d0;
    float a0=0.f, a1=0.f;
    #pragma unroll 8
    for (int s=0;s<64;s++){
      float w = wrow[s];
      float2 v = *(const float2*)(xb + (size_t)s*DQ);
      a0 += w*v.x; a1 += w*v.y;
    }
    *(float2*)(part + (size_t)bm*DQ + d0) = make_float2(a0,a1);
  }
}

// ---- final: out[b][d] = sum_c part[b*32+c][d] / sum_c wsum[b*32+c]
__global__ __launch_bounds__(256) void k_fin(const float* __restrict__ part,
                                             const float* __restrict__ wsum,
                                             float* __restrict__ out){
  int i = blockIdx.x*256 + threadIdx.x;   // 32768
  int b = i >> 10, d = i & 1023;
  float den = 0.f;
  #pragma unroll
  for (int c=0;c<32;c++) den += wsum[b*32+c];
  float s = 0.f;
  #pragma unroll
  for (int c=0;c<32;c++) s += part[((size_t)(b*32+c))*DQ + d];
  out[i] = s/den;
}

extern "C" void kernel_launch(void* const* d_in, const int* in_sizes, int n_in,
                              void* d_out, int out_size, void* d_ws, size_t ws_size,
                              hipStream_t stream)
{
  const float* x    = (const float*)d_in[0];
  const void*  mask = d_in[1];
  const float* w1   = (const float*)d_in[2];
  const float* b1   = (const float*)d_in[3];
  const float* w2   = (const float*)d_in[4];
  const float* b2   = (const float*)d_in[5];
  const float* lam  = (const float*)d_in[6];
  const float* q    = (const float*)d_in[7];
  const float* kw   = (const float*)d_in[8];
  const float* kb   = (const float*)d_in[9];
  char* ws = (char*)d_ws;
  short* w1t = (short*)ws;                               // 1 MB
  float* wq  = (float*)(ws + (1<<20));                   // 8 KB (1025 floats)
  int* flag  = (int*)(ws + (1<<20) + 8192);              // 4 B
  int* lens  = (int*)(ws + (1<<20) + 8448);              // 128 B
  float* wsum= (float*)(ws + (1<<20) + 12544);           // 4 KB (1024 floats)
  float* part= (float*)(ws + (1<<20) + 20736);           // 4 MB
  float* out = (float*)d_out;

  k_w1t<<<dim3((NQ*DQ+255)/256), 256, 0, stream>>>(w1, w1t);
  k_wq<<<dim3(DQ+1), 256, 0, stream>>>(kw, kb, q, wq);
  k_det<<<dim3(1), 256, 0, stream>>>((const unsigned int*)mask, flag);
  k_len<<<dim3(BQ), 256, 0, stream>>>(mask, flag, lens);
  k_gate<<<dim3(MQ/BM), 512, 0, stream>>>(x, w1t, wq, w2, b1, b2, lam,
                                          mask, flag, lens, part, wsum);
  k_fin<<<dim3((BQ*DQ)/256), 256, 0, stream>>>(part, wsum, out);
}